// Round 2
// baseline (386.471 us; speedup 1.0000x reference)
//
#include <hip/hip_runtime.h>

typedef short bf16x8 __attribute__((ext_vector_type(8)));
typedef float f32x4 __attribute__((ext_vector_type(4)));

#define NBJ 16          // BS*J
#define NMT 125         // 2000/16 m-tiles
#define NKT 63          // ceil(2000/32) k-tiles
#define NCH 128         // J*C channels
#define NM  2000
#define NB  4
#define NJ  4
#define NC  32
#define BN_EPS 1e-5f

// ---- helpers: fp32 -> bf16 (RNE) hi, and residual lo ----
__device__ inline void bf16_split(float v, short& hi, short& lo) {
    unsigned u = __float_as_uint(v);
    unsigned rn = (u + 0x7fffu + ((u >> 16) & 1u)) & 0xffff0000u;
    hi = (short)(rn >> 16);
    float d = v - __uint_as_float(rn);
    unsigned ud = __float_as_uint(d);
    lo = (short)((ud + 0x7fffu + ((ud >> 16) & 1u)) >> 16);
}

// ---- kernel 1: build x fragments in MFMA B-operand layout; zero stats ----
// B-frag for 16x16x32: lane holds B[k = (lane>>4)*8 + j][n = lane&15], j=0..7
__global__ __launch_bounds__(256) void prep_kernel(
        const float* __restrict__ x, short* __restrict__ xfrag,
        float* __restrict__ csum /* csum[128] then csumsq[128] contiguous */) {
    int gid = blockIdx.x * 256 + threadIdx.x;     // 0..32255
    if (gid < 256) csum[gid] = 0.f;
    int lane = gid & 63;
    int t = gid >> 6;
    int ct = t & 1; t >>= 1;
    int kt = t % NKT;
    int b  = t / NKT;
    int c  = ct * 16 + (lane & 15);
    int k0 = kt * 32 + (lane >> 4) * 8;
    const float* xp = x + ((size_t)b * NC + c) * NM;
    bf16x8 hi, lo;
#pragma unroll
    for (int j = 0; j < 8; ++j) {
        int k = k0 + j;
        float v = (k < NM) ? xp[k] : 0.f;
        short h, l;
        bf16_split(v, h, l);
        hi[j] = h; lo[j] = l;
    }
    size_t base = ((((size_t)b * NKT + kt) * 2 + ct) * 2) * 512 + (size_t)lane * 8;
    *(bf16x8*)(xfrag + base)       = hi;
    *(bf16x8*)(xfrag + base + 512) = lo;
}

// guarded W-tile load: kt==62 covers k 1984..2015, quads 2,3 OOB -> zeros
__device__ inline void loadA(const float* __restrict__ wp, int t, int quad,
                             float4& a0, float4& a1) {
    float4 z = make_float4(0.f, 0.f, 0.f, 0.f);
    a0 = z; a1 = z;
    if ((t < NKT - 1) | (quad < 2)) {
        const float* p = wp + (size_t)t * 32;
        a0 = *(const float4*)p;
        a1 = *(const float4*)(p + 4);
    }
}

// ---- kernel 2: GEMM y[bj][m][c] = sum_n W[bj][m][n] * x[b][c][n], fused stats ----
__global__ __launch_bounds__(256) void gemm_kernel(
        const float* __restrict__ W, const short* __restrict__ xfrag,
        float* __restrict__ y, float* __restrict__ csum, float* __restrict__ csumsq) {
    const int lane = threadIdx.x & 63;
    const int wid  = (blockIdx.x << 2) + (threadIdx.x >> 6);   // 0..1999
    const int bj = wid / NMT;
    const int mt = wid - bj * NMT;
    const int b  = bj >> 2;
    const int quad = lane >> 4;
    const int r = lane & 15;

    const float* wp = W + ((size_t)bj * NM + mt * 16 + r) * NM + quad * 8;
    const short* xb = xfrag + (size_t)b * NKT * 2048;   // 2048 shorts per k-tile
    const int loff = lane * 8;

    f32x4 acc0 = {0.f, 0.f, 0.f, 0.f};
    f32x4 acc1 = {0.f, 0.f, 0.f, 0.f};

#define BFRAG(kt, ct, hl) (*(const bf16x8*)(xb + (size_t)(kt) * 2048 + (ct) * 1024 + (hl) * 512 + loff))

    // 2-deep pipeline on the HBM-resident W stream
    float4 c00, c01, c10, c11;
    loadA(wp, 0, quad, c00, c01);
    loadA(wp, 1, quad, c10, c11);
    // 1-deep on the L2-resident xfrag stream
    bf16x8 bh0 = BFRAG(0, 0, 0), bl0 = BFRAG(0, 0, 1);
    bf16x8 bh1 = BFRAG(0, 1, 0), bl1 = BFRAG(0, 1, 1);

    for (int kt = 0; kt < NKT; ++kt) {
        float4 c20, c21;
        if (kt + 2 < NKT) {
            loadA(wp, kt + 2, quad, c20, c21);
        } else {
            c20 = make_float4(0.f, 0.f, 0.f, 0.f); c21 = c20;
        }
        bf16x8 nh0, nl0, nh1, nl1;
        if (kt + 1 < NKT) {
            nh0 = BFRAG(kt + 1, 0, 0); nl0 = BFRAG(kt + 1, 0, 1);
            nh1 = BFRAG(kt + 1, 1, 0); nl1 = BFRAG(kt + 1, 1, 1);
        }
        // convert current A tile fp32 -> hi/lo bf16 frags
        bf16x8 ah, al;
        float v[8] = {c00.x, c00.y, c00.z, c00.w, c01.x, c01.y, c01.z, c01.w};
#pragma unroll
        for (int j = 0; j < 8; ++j) {
            short h, l;
            bf16_split(v[j], h, l);
            ah[j] = h; al[j] = l;
        }
        acc0 = __builtin_amdgcn_mfma_f32_16x16x32_bf16(ah, bh0, acc0, 0, 0, 0);
        acc1 = __builtin_amdgcn_mfma_f32_16x16x32_bf16(ah, bh1, acc1, 0, 0, 0);
        acc0 = __builtin_amdgcn_mfma_f32_16x16x32_bf16(al, bh0, acc0, 0, 0, 0);
        acc1 = __builtin_amdgcn_mfma_f32_16x16x32_bf16(al, bh1, acc1, 0, 0, 0);
        acc0 = __builtin_amdgcn_mfma_f32_16x16x32_bf16(ah, bl0, acc0, 0, 0, 0);
        acc1 = __builtin_amdgcn_mfma_f32_16x16x32_bf16(ah, bl1, acc1, 0, 0, 0);
        c00 = c10; c01 = c11; c10 = c20; c11 = c21;
        if (kt + 1 < NKT) {
            bh0 = nh0; bl0 = nl0; bh1 = nh1; bl1 = nl1;
        }
    }

    // ---- fused per-channel stats: sum + sumsq over the 16 rows of this tile ----
    // D layout: col = lane&15 (channel within ctile), row = quad*4 + reg
    float s0 = acc0[0] + acc0[1] + acc0[2] + acc0[3];
    float q0 = acc0[0]*acc0[0] + acc0[1]*acc0[1] + acc0[2]*acc0[2] + acc0[3]*acc0[3];
    float s1 = acc1[0] + acc1[1] + acc1[2] + acc1[3];
    float q1 = acc1[0]*acc1[0] + acc1[1]*acc1[1] + acc1[2]*acc1[2] + acc1[3]*acc1[3];
    s0 += __shfl_xor(s0, 16); s0 += __shfl_xor(s0, 32);
    q0 += __shfl_xor(q0, 16); q0 += __shfl_xor(q0, 32);
    s1 += __shfl_xor(s1, 16); s1 += __shfl_xor(s1, 32);
    q1 += __shfl_xor(q1, 16); q1 += __shfl_xor(q1, 32);
    const int j = bj & 3;
    if (quad == 0) {
        atomicAdd(&csum[j * NC + r], s0);
        atomicAdd(&csumsq[j * NC + r], q0);
        atomicAdd(&csum[j * NC + 16 + r], s1);
        atomicAdd(&csumsq[j * NC + 16 + r], q1);
    }

    // ---- store y tile: y[bj][m][c], c contiguous (32 floats per m) ----
    float* yp = y + ((size_t)bj * NM + mt * 16 + quad * 4) * NC + r;
#pragma unroll
    for (int i = 0; i < 4; ++i) {
        yp[i * NC]      = acc0[i];
        yp[i * NC + 16] = acc1[i];
    }
}

// ---- kernel 3: BN (from stats) + ReLU + 1x1 conv, LDS-staged ----
// grid = 63 m-tiles (32 rows each) x 4 batches = 252 blocks, 256 threads
#define MT 32
__global__ __launch_bounds__(256) void conv_kernel(
        const float* __restrict__ y, const float* __restrict__ csum,
        const float* __restrict__ csumsq, const float* __restrict__ gamma,
        const float* __restrict__ beta, const float* __restrict__ conv_w,
        const float* __restrict__ conv_b, float* __restrict__ out) {
    __shared__ float ya[MT][NCH + 1];    // +1 pad: break 32-bank aliasing
    __shared__ float wt[NCH * 32];       // wt[jc*32 + o] = conv_w[o*128 + jc]
    __shared__ float sscale[NCH], sshift[NCH], scb[32];
    const int t = threadIdx.x;
    const int b  = blockIdx.x & 3;
    const int m0 = (blockIdx.x >> 2) * MT;

    if (t < NCH) {
        const float inv = 1.f / (NB * NM);
        float mean = csum[t] * inv;
        float var = csumsq[t] * inv - mean * mean;
        var = fmaxf(var, 0.f);
        float rs = rsqrtf(var + BN_EPS);
        float sc = gamma[t] * rs;
        sscale[t] = sc;
        sshift[t] = beta[t] - mean * sc;
    }
    if (t < 32) scb[t] = conv_b[t];
#pragma unroll
    for (int i = t; i < NCH * 32; i += 256)
        wt[i] = conv_w[(i & 31) * NCH + (i >> 5)];
    __syncthreads();

    // stage BN+ReLU'd y tile: ya[m_local][jc], float4 coalesced loads
#pragma unroll
    for (int i = t; i < 1024; i += 256) {
        int jj = i >> 8;                 // 0..3
        int e  = (i & 255) * 4;          // element within [MT][32]
        int ml = e >> 5, c = e & 31;
        int m  = m0 + ml;
        float4 v = make_float4(0.f, 0.f, 0.f, 0.f);
        if (m < NM)
            v = *(const float4*)(y + (((size_t)b * NJ + jj) * NM + m) * NC + c);
        int jc = jj * 32 + c;
        ya[ml][jc    ] = fmaxf(fmaf(v.x, sscale[jc    ], sshift[jc    ]), 0.f);
        ya[ml][jc + 1] = fmaxf(fmaf(v.y, sscale[jc + 1], sshift[jc + 1]), 0.f);
        ya[ml][jc + 2] = fmaxf(fmaf(v.z, sscale[jc + 2], sshift[jc + 2]), 0.f);
        ya[ml][jc + 3] = fmaxf(fmaf(v.w, sscale[jc + 3], sshift[jc + 3]), 0.f);
    }
    __syncthreads();

    const int o_hi = t >> 5;             // 0..7 -> o = o_hi*4 + u
    const int ml   = t & 31;
    float acc[4];
#pragma unroll
    for (int u = 0; u < 4; ++u) acc[u] = scb[o_hi * 4 + u];

#pragma unroll 4
    for (int jc = 0; jc < NCH; ++jc) {
        float v = ya[ml][jc];                              // broadcast across o_hi
        float4 w4 = *(const float4*)&wt[jc * 32 + o_hi * 4]; // ds_read_b128
        acc[0] = fmaf(v, w4.x, acc[0]);
        acc[1] = fmaf(v, w4.y, acc[1]);
        acc[2] = fmaf(v, w4.z, acc[2]);
        acc[3] = fmaf(v, w4.w, acc[3]);
    }
    int m = m0 + ml;
    if (m < NM) {
#pragma unroll
        for (int u = 0; u < 4; ++u)
            out[((size_t)b * 32 + o_hi * 4 + u) * NM + m] = acc[u];
    }
}

extern "C" void kernel_launch(void* const* d_in, const int* in_sizes, int n_in,
                              void* d_out, int out_size, void* d_ws, size_t ws_size,
                              hipStream_t stream) {
    const float* W      = (const float*)d_in[0];
    const float* x      = (const float*)d_in[1];
    const float* gamma  = (const float*)d_in[2];
    const float* beta   = (const float*)d_in[3];
    const float* conv_w = (const float*)d_in[4];
    const float* conv_b = (const float*)d_in[5];
    float* out = (float*)d_out;

    char* ws = (char*)d_ws;
    float* y      = (float*)ws;                  // 16*2000*32 fp32 = 4,096,000 B
    float* csum   = (float*)(ws + 4096000);      // 128 fp32
    float* csumsq = (float*)(ws + 4096512);      // 128 fp32
    short* xfrag  = (short*)(ws + 4097024);      // 4*63*2*2*512 shorts = 1,032,192 B

    prep_kernel<<<126, 256, 0, stream>>>(x, xfrag, csum);
    gemm_kernel<<<500, 256, 0, stream>>>(W, xfrag, y, csum, csumsq);
    conv_kernel<<<252, 256, 0, stream>>>(y, csum, csumsq, gamma, beta, conv_w, conv_b, out);
}

// Round 3
// 373.384 us; speedup vs baseline: 1.0350x; 1.0350x over previous
//
#include <hip/hip_runtime.h>

typedef short bf16x8 __attribute__((ext_vector_type(8)));
typedef float f32x4 __attribute__((ext_vector_type(4)));

#define NBJ 16          // BS*J
#define NMT 125         // 2000/16 m-tiles
#define NKT 63          // ceil(2000/32) k-tiles
#define NCH 128         // J*C channels
#define NM  2000
#define NB  4
#define NJ  4
#define NC  32
#define BN_EPS 1e-5f

// ---- truncation hi/lo split: hi = trunc16(v), lo = trunc16(v - hi) ----
// captures ~16 mantissa bits across the pair; cheap (no rounding adds)
__device__ inline void bf16_split_tr(float v, short& hi, short& lo) {
    unsigned u = __float_as_uint(v);
    hi = (short)(u >> 16);
    float d = v - __uint_as_float(u & 0xffff0000u);
    lo = (short)(__float_as_uint(d) >> 16);
}

// RNE split for the tiny prep kernel (cost irrelevant there)
__device__ inline void bf16_split(float v, short& hi, short& lo) {
    unsigned u = __float_as_uint(v);
    unsigned rn = (u + 0x7fffu + ((u >> 16) & 1u)) & 0xffff0000u;
    hi = (short)(rn >> 16);
    float d = v - __uint_as_float(rn);
    unsigned ud = __float_as_uint(d);
    lo = (short)((ud + 0x7fffu + ((ud >> 16) & 1u)) >> 16);
}

// ---- kernel 1: build x fragments in MFMA B-operand layout; zero stats ----
// B-frag for 16x16x32: lane holds B[k = (lane>>4)*8 + j][n = lane&15], j=0..7
__global__ __launch_bounds__(256) void prep_kernel(
        const float* __restrict__ x, short* __restrict__ xfrag,
        float* __restrict__ csum /* csum[128] then csumsq[128] contiguous */) {
    int gid = blockIdx.x * 256 + threadIdx.x;     // 0..32255
    if (gid < 256) csum[gid] = 0.f;
    int lane = gid & 63;
    int t = gid >> 6;
    int ct = t & 1; t >>= 1;
    int kt = t % NKT;
    int b  = t / NKT;
    int c  = ct * 16 + (lane & 15);
    int k0 = kt * 32 + (lane >> 4) * 8;
    const float* xp = x + ((size_t)b * NC + c) * NM;
    bf16x8 hi, lo;
#pragma unroll
    for (int j = 0; j < 8; ++j) {
        int k = k0 + j;
        float v = (k < NM) ? xp[k] : 0.f;
        short h, l;
        bf16_split(v, h, l);
        hi[j] = h; lo[j] = l;
    }
    size_t base = ((((size_t)b * NKT + kt) * 2 + ct) * 2) * 512 + (size_t)lane * 8;
    *(bf16x8*)(xfrag + base)       = hi;
    *(bf16x8*)(xfrag + base + 512) = lo;
}

// ---- kernel 2: GEMM y[bj][m][c] = sum_n W[bj][m][n] * x[b][c][n], fused stats ----
// 1 wave = one 16-row m-tile x all 32 channels. Branch-free main K-loop over the
// 62 full k-tiles (#pragma unroll 2 -> register renaming, no copy chain);
// half-tile tail (k=1984..1999) in a separate epilogue.
__global__ __launch_bounds__(256) void gemm_kernel(
        const float* __restrict__ W, const short* __restrict__ xfrag,
        float* __restrict__ y, float* __restrict__ csum, float* __restrict__ csumsq) {
    const int lane = threadIdx.x & 63;
    const int wid  = (blockIdx.x << 2) + (threadIdx.x >> 6);   // 0..1999
    const int bj = wid / NMT;
    const int mt = wid - bj * NMT;
    const int b  = bj >> 2;
    const int quad = lane >> 4;
    const int r = lane & 15;

    const float* wp = W + ((size_t)bj * NM + mt * 16 + r) * NM + quad * 8;
    const short* xb = xfrag + (size_t)b * NKT * 2048;   // 2048 shorts per k-tile
    const int loff = lane * 8;

    f32x4 acc0 = {0.f, 0.f, 0.f, 0.f};
    f32x4 acc1 = {0.f, 0.f, 0.f, 0.f};

#define BFRAG(kt, ct, hl) (*(const bf16x8*)(xb + (size_t)(kt) * 2048 + (ct) * 1024 + (hl) * 512 + loff))
#define SPLIT8(A0, A1, AH, AL) do {                                   \
        float _v[8] = {A0.x, A0.y, A0.z, A0.w, A1.x, A1.y, A1.z, A1.w}; \
        _Pragma("unroll")                                              \
        for (int _j = 0; _j < 8; ++_j) {                               \
            short _h, _l; bf16_split_tr(_v[_j], _h, _l);               \
            AH[_j] = _h; AL[_j] = _l;                                  \
        }                                                              \
    } while (0)
#define MFMA6(AH, AL, BH0, BL0, BH1, BL1) do {                                   \
        acc0 = __builtin_amdgcn_mfma_f32_16x16x32_bf16(AH, BH0, acc0, 0, 0, 0);  \
        acc1 = __builtin_amdgcn_mfma_f32_16x16x32_bf16(AH, BH1, acc1, 0, 0, 0);  \
        acc0 = __builtin_amdgcn_mfma_f32_16x16x32_bf16(AL, BH0, acc0, 0, 0, 0);  \
        acc1 = __builtin_amdgcn_mfma_f32_16x16x32_bf16(AL, BH1, acc1, 0, 0, 0);  \
        acc0 = __builtin_amdgcn_mfma_f32_16x16x32_bf16(AH, BL0, acc0, 0, 0, 0);  \
        acc1 = __builtin_amdgcn_mfma_f32_16x16x32_bf16(AH, BL1, acc1, 0, 0, 0);  \
    } while (0)

    // depth-2 prefetch on W (HBM), depth-1 on xfrag (L2)
    float4 a0c = *(const float4*)(wp);
    float4 a1c = *(const float4*)(wp + 4);
    float4 a0n = *(const float4*)(wp + 32);
    float4 a1n = *(const float4*)(wp + 36);
    bf16x8 bh0 = BFRAG(0, 0, 0), bl0 = BFRAG(0, 0, 1);
    bf16x8 bh1 = BFRAG(0, 1, 0), bl1 = BFRAG(0, 1, 1);

#pragma unroll 2
    for (int kt = 0; kt < 62; ++kt) {
        int ktp = kt + 2; ktp = (ktp > 61) ? 61 : ktp;     // uniform clamp, branch-free
        const float* pp = wp + (size_t)ktp * 32;
        float4 p0 = *(const float4*)(pp);
        float4 p1 = *(const float4*)(pp + 4);
        bf16x8 nh0 = BFRAG(kt + 1, 0, 0), nl0 = BFRAG(kt + 1, 0, 1);
        bf16x8 nh1 = BFRAG(kt + 1, 1, 0), nl1 = BFRAG(kt + 1, 1, 1);

        bf16x8 ah, al;
        SPLIT8(a0c, a1c, ah, al);
        MFMA6(ah, al, bh0, bl0, bh1, bl1);

        a0c = a0n; a1c = a1n; a0n = p0; a1n = p1;          // renamed away by unroll
        bh0 = nh0; bl0 = nl0; bh1 = nh1; bl1 = nl1;
    }

    // tail k-tile 62: k = 1984..1999 (quads 0,1); quads 2,3 contribute zero.
    // bh0..bl1 currently hold xfrag tile 62 (loaded at kt=61).
    {
        float4 t0 = make_float4(0.f, 0.f, 0.f, 0.f), t1 = t0;
        if (quad < 2) {
            const float* tp = wp + (size_t)62 * 32;
            t0 = *(const float4*)(tp);
            t1 = *(const float4*)(tp + 4);
        }
        bf16x8 ah, al;
        SPLIT8(t0, t1, ah, al);
        MFMA6(ah, al, bh0, bl0, bh1, bl1);
    }

    // ---- fused per-channel stats: sum + sumsq over the 16 rows of this tile ----
    // D layout: col = lane&15 (channel within ctile), row = quad*4 + reg
    float s0 = acc0[0] + acc0[1] + acc0[2] + acc0[3];
    float q0 = acc0[0]*acc0[0] + acc0[1]*acc0[1] + acc0[2]*acc0[2] + acc0[3]*acc0[3];
    float s1 = acc1[0] + acc1[1] + acc1[2] + acc1[3];
    float q1 = acc1[0]*acc1[0] + acc1[1]*acc1[1] + acc1[2]*acc1[2] + acc1[3]*acc1[3];
    s0 += __shfl_xor(s0, 16); s0 += __shfl_xor(s0, 32);
    q0 += __shfl_xor(q0, 16); q0 += __shfl_xor(q0, 32);
    s1 += __shfl_xor(s1, 16); s1 += __shfl_xor(s1, 32);
    q1 += __shfl_xor(q1, 16); q1 += __shfl_xor(q1, 32);
    const int j = bj & 3;
    if (quad == 0) {
        atomicAdd(&csum[j * NC + r], s0);
        atomicAdd(&csumsq[j * NC + r], q0);
        atomicAdd(&csum[j * NC + 16 + r], s1);
        atomicAdd(&csumsq[j * NC + 16 + r], q1);
    }

    // ---- store y tile: y[bj][m][c], c contiguous (32 floats per m) ----
    float* yp = y + ((size_t)bj * NM + mt * 16 + quad * 4) * NC + r;
#pragma unroll
    for (int i = 0; i < 4; ++i) {
        yp[i * NC]      = acc0[i];
        yp[i * NC + 16] = acc1[i];
    }
}

// ---- kernel 3: BN (from stats) + ReLU + 1x1 conv, LDS-staged ----
// grid = 63 m-tiles (32 rows each) x 4 batches = 252 blocks, 256 threads
#define MT 32
__global__ __launch_bounds__(256) void conv_kernel(
        const float* __restrict__ y, const float* __restrict__ csum,
        const float* __restrict__ csumsq, const float* __restrict__ gamma,
        const float* __restrict__ beta, const float* __restrict__ conv_w,
        const float* __restrict__ conv_b, float* __restrict__ out) {
    __shared__ float ya[MT][NCH + 1];    // +1 pad: break 32-bank aliasing
    __shared__ float wt[NCH * 32];       // wt[jc*32 + o] = conv_w[o*128 + jc]
    __shared__ float sscale[NCH], sshift[NCH], scb[32];
    const int t = threadIdx.x;
    const int b  = blockIdx.x & 3;
    const int m0 = (blockIdx.x >> 2) * MT;

    if (t < NCH) {
        const float inv = 1.f / (NB * NM);
        float mean = csum[t] * inv;
        float var = csumsq[t] * inv - mean * mean;
        var = fmaxf(var, 0.f);
        float rs = rsqrtf(var + BN_EPS);
        float sc = gamma[t] * rs;
        sscale[t] = sc;
        sshift[t] = beta[t] - mean * sc;
    }
    if (t < 32) scb[t] = conv_b[t];
#pragma unroll
    for (int i = t; i < NCH * 32; i += 256)
        wt[i] = conv_w[(i & 31) * NCH + (i >> 5)];
    __syncthreads();

    // stage BN+ReLU'd y tile: ya[m_local][jc], float4 coalesced loads
#pragma unroll
    for (int i = t; i < 1024; i += 256) {
        int jj = i >> 8;                 // 0..3
        int e  = (i & 255) * 4;          // element within [MT][32]
        int ml = e >> 5, c = e & 31;
        int m  = m0 + ml;
        float4 v = make_float4(0.f, 0.f, 0.f, 0.f);
        if (m < NM)
            v = *(const float4*)(y + (((size_t)b * NJ + jj) * NM + m) * NC + c);
        int jc = jj * 32 + c;
        ya[ml][jc    ] = fmaxf(fmaf(v.x, sscale[jc    ], sshift[jc    ]), 0.f);
        ya[ml][jc + 1] = fmaxf(fmaf(v.y, sscale[jc + 1], sshift[jc + 1]), 0.f);
        ya[ml][jc + 2] = fmaxf(fmaf(v.z, sscale[jc + 2], sshift[jc + 2]), 0.f);
        ya[ml][jc + 3] = fmaxf(fmaf(v.w, sscale[jc + 3], sshift[jc + 3]), 0.f);
    }
    __syncthreads();

    const int o_hi = t >> 5;             // 0..7 -> o = o_hi*4 + u
    const int ml   = t & 31;
    float acc[4];
#pragma unroll
    for (int u = 0; u < 4; ++u) acc[u] = scb[o_hi * 4 + u];

#pragma unroll 4
    for (int jc = 0; jc < NCH; ++jc) {
        float v = ya[ml][jc];                                // broadcast across o_hi
        float4 w4 = *(const float4*)&wt[jc * 32 + o_hi * 4]; // ds_read_b128
        acc[0] = fmaf(v, w4.x, acc[0]);
        acc[1] = fmaf(v, w4.y, acc[1]);
        acc[2] = fmaf(v, w4.z, acc[2]);
        acc[3] = fmaf(v, w4.w, acc[3]);
    }
    int m = m0 + ml;
    if (m < NM) {
#pragma unroll
        for (int u = 0; u < 4; ++u)
            out[((size_t)b * 32 + o_hi * 4 + u) * NM + m] = acc[u];
    }
}

extern "C" void kernel_launch(void* const* d_in, const int* in_sizes, int n_in,
                              void* d_out, int out_size, void* d_ws, size_t ws_size,
                              hipStream_t stream) {
    const float* W      = (const float*)d_in[0];
    const float* x      = (const float*)d_in[1];
    const float* gamma  = (const float*)d_in[2];
    const float* beta   = (const float*)d_in[3];
    const float* conv_w = (const float*)d_in[4];
    const float* conv_b = (const float*)d_in[5];
    float* out = (float*)d_out;

    char* ws = (char*)d_ws;
    float* y      = (float*)ws;                  // 16*2000*32 fp32 = 4,096,000 B
    float* csum   = (float*)(ws + 4096000);      // 128 fp32
    float* csumsq = (float*)(ws + 4096512);      // 128 fp32
    short* xfrag  = (short*)(ws + 4097024);      // 4*63*2*2*512 shorts = 1,032,192 B

    prep_kernel<<<126, 256, 0, stream>>>(x, xfrag, csum);
    gemm_kernel<<<500, 256, 0, stream>>>(W, xfrag, y, csum, csumsq);
    conv_kernel<<<252, 256, 0, stream>>>(y, csum, csumsq, gamma, beta, conv_w, conv_b, out);
}